// Round 1
// baseline (2851.763 us; speedup 1.0000x reference)
//
#include <hip/hip_runtime.h>
#include <math.h>

#define N_NODES 100000
#define N_EDGES 1600000
#define F_OUT 16

// ---------------------------------------------------------------------------
// zero a float region
__global__ void zero_kernel(float* __restrict__ p, int n) {
    int i = blockIdx.x * blockDim.x + threadIdx.x;
    if (i < n) p[i] = 0.0f;
}

// ---------------------------------------------------------------------------
// Per-node transform:
//   Y0 = X @ W[0]          (N, 16)
//   Y1 = X @ (W[1]-W[0])   (N, 16)
//   R  = X @ root + bias   (N, 16)
// One thread per (node, out_feat). Weights staged in LDS.
__global__ void node_transform(const float* __restrict__ X, int fin,
                               const float* __restrict__ W,     // (2, fin, 16)
                               const float* __restrict__ root,  // (fin, 16)
                               const float* __restrict__ bias,  // (16)
                               float* __restrict__ Y0,
                               float* __restrict__ Y1,
                               float* __restrict__ R,
                               int n_nodes) {
    __shared__ float sW0[48 * 16];
    __shared__ float sWd[48 * 16];
    __shared__ float sR[48 * 16];
    __shared__ float sB[16];
    int t = threadIdx.x;
    for (int i = t; i < fin * 16; i += blockDim.x) {
        float w0 = W[i];
        float w1 = W[fin * 16 + i];
        sW0[i] = w0;
        sWd[i] = w1 - w0;
        sR[i]  = root[i];
    }
    if (t < 16) sB[t] = bias[t];
    __syncthreads();

    int idx = blockIdx.x * blockDim.x + t;
    int n = idx >> 4;
    int o = idx & 15;
    if (n >= n_nodes) return;

    const float* xr = X + (long)n * fin;
    float a0 = 0.0f, a1 = 0.0f, ar = 0.0f;
    for (int f = 0; f < fin; ++f) {
        float xv = xr[f];
        a0 = fmaf(xv, sW0[f * 16 + o], a0);
        a1 = fmaf(xv, sWd[f * 16 + o], a1);
        ar = fmaf(xv, sR[f * 16 + o], ar);
    }
    Y0[idx] = a0;
    Y1[idx] = a1;
    R[idx]  = ar + sB[o];
}

// ---------------------------------------------------------------------------
// Per-edge: msg = Y0[src] + u * Y1[src]; atomically accumulate into acc[dst].
// Optionally also count edges per destination.
__global__ void edge_aggregate(const int* __restrict__ src,
                               const int* __restrict__ dst,
                               const float* __restrict__ u,
                               const float* __restrict__ Y0,
                               const float* __restrict__ Y1,
                               float* __restrict__ acc,
                               float* __restrict__ cnt,
                               int do_cnt) {
    int e = blockIdx.x * blockDim.x + threadIdx.x;
    if (e >= N_EDGES) return;
    int s = src[e];
    int d = dst[e];
    float uu = u[e];
    const float4* y0 = (const float4*)(Y0 + (long)s * 16);
    const float4* y1 = (const float4*)(Y1 + (long)s * 16);
    float* ap = acc + (long)d * 16;
#pragma unroll
    for (int q = 0; q < 4; ++q) {
        float4 a = y0[q];
        float4 b = y1[q];
        atomicAdd(ap + 4 * q + 0, fmaf(uu, b.x, a.x));
        atomicAdd(ap + 4 * q + 1, fmaf(uu, b.y, a.y));
        atomicAdd(ap + 4 * q + 2, fmaf(uu, b.z, a.z));
        atomicAdd(ap + 4 * q + 3, fmaf(uu, b.w, a.w));
    }
    if (do_cnt) atomicAdd(cnt + d, 1.0f);
}

// ---------------------------------------------------------------------------
// h = elu(acc / max(cnt,1) + r)
__global__ void finalize_elu(const float* __restrict__ acc,
                             const float* __restrict__ cnt,
                             const float* __restrict__ r,
                             float* __restrict__ h) {
    int idx = blockIdx.x * blockDim.x + threadIdx.x;
    if (idx >= N_NODES * F_OUT) return;
    int n = idx >> 4;
    float c = cnt[n];
    c = c < 1.0f ? 1.0f : c;
    float v = acc[idx] / c + r[idx];
    h[idx] = v > 0.0f ? v : expm1f(v);
}

// ---------------------------------------------------------------------------
// out = log_softmax(acc / max(cnt,1) + r) over the 16 features of each node
__global__ void finalize_logsoftmax(const float* __restrict__ acc,
                                    const float* __restrict__ cnt,
                                    const float* __restrict__ r,
                                    float* __restrict__ out) {
    int n = blockIdx.x * blockDim.x + threadIdx.x;
    if (n >= N_NODES) return;
    float c = cnt[n];
    c = c < 1.0f ? 1.0f : c;
    float inv = 1.0f / c;

    float v[16];
    const float4* ap = (const float4*)(acc + (long)n * 16);
    const float4* rp = (const float4*)(r + (long)n * 16);
    float m = -INFINITY;
#pragma unroll
    for (int q = 0; q < 4; ++q) {
        float4 a = ap[q];
        float4 rr = rp[q];
        v[4 * q + 0] = fmaf(a.x, inv, rr.x);
        v[4 * q + 1] = fmaf(a.y, inv, rr.y);
        v[4 * q + 2] = fmaf(a.z, inv, rr.z);
        v[4 * q + 3] = fmaf(a.w, inv, rr.w);
    }
#pragma unroll
    for (int i = 0; i < 16; ++i) m = fmaxf(m, v[i]);
    float s = 0.0f;
#pragma unroll
    for (int i = 0; i < 16; ++i) s += expf(v[i] - m);
    float lse = m + logf(s);

    float4* op = (float4*)(out + (long)n * 16);
#pragma unroll
    for (int q = 0; q < 4; ++q) {
        float4 o;
        o.x = v[4 * q + 0] - lse;
        o.y = v[4 * q + 1] - lse;
        o.z = v[4 * q + 2] - lse;
        o.w = v[4 * q + 3] - lse;
        op[q] = o;
    }
}

// ---------------------------------------------------------------------------
extern "C" void kernel_launch(void* const* d_in, const int* in_sizes, int n_in,
                              void* d_out, int out_size, void* d_ws, size_t ws_size,
                              hipStream_t stream) {
    const float* x         = (const float*)d_in[0];  // (N, 48)
    const float* edge_attr = (const float*)d_in[1];  // (E, 1)
    const int*   edge_idx  = (const int*)d_in[2];    // (2, E)
    const float* W1        = (const float*)d_in[3];  // (2, 48, 16)
    const float* root1     = (const float*)d_in[4];  // (48, 16)
    const float* b1        = (const float*)d_in[5];  // (16)
    const float* W2        = (const float*)d_in[6];  // (2, 16, 16)
    const float* root2     = (const float*)d_in[7];  // (16, 16)
    const float* b2        = (const float*)d_in[8];  // (16)
    float* out = (float*)d_out;

    const int* src = edge_idx;            // edge_index[0]
    const int* dst = edge_idx + N_EDGES;  // edge_index[1]

    const size_t NF = (size_t)N_NODES * F_OUT;  // 1.6M floats
    float* ws = (float*)d_ws;
    float* bufA = ws + 0 * NF;  // Y0
    float* bufB = ws + 1 * NF;  // Y1
    float* bufC = ws + 2 * NF;  // R
    float* bufD = ws + 3 * NF;  // acc (followed directly by cnt)
    float* cntp = ws + 4 * NF;  // cnt (N floats)
    float* bufE = ws + 4 * NF + N_NODES;  // h

    const int BLK = 256;
    dim3 blk(BLK);
    dim3 gEdges((N_EDGES + BLK - 1) / BLK);
    dim3 gNF(((int)NF + BLK - 1) / BLK);
    dim3 gNodes((N_NODES + BLK - 1) / BLK);
    dim3 gZero1(((int)NF + N_NODES + BLK - 1) / BLK);

    // ---- layer 1 ----
    zero_kernel<<<gZero1, blk, 0, stream>>>(bufD, (int)NF + N_NODES);  // acc + cnt
    node_transform<<<gNF, blk, 0, stream>>>(x, 48, W1, root1, b1,
                                            bufA, bufB, bufC, N_NODES);
    edge_aggregate<<<gEdges, blk, 0, stream>>>(src, dst, edge_attr,
                                               bufA, bufB, bufD, cntp, 1);
    finalize_elu<<<gNF, blk, 0, stream>>>(bufD, cntp, bufC, bufE);

    // ---- layer 2 ----
    zero_kernel<<<gNF, blk, 0, stream>>>(bufD, (int)NF);
    node_transform<<<gNF, blk, 0, stream>>>(bufE, 16, W2, root2, b2,
                                            bufA, bufB, bufC, N_NODES);
    edge_aggregate<<<gEdges, blk, 0, stream>>>(src, dst, edge_attr,
                                               bufA, bufB, bufD, cntp, 0);
    finalize_logsoftmax<<<gNodes, blk, 0, stream>>>(bufD, cntp, bufC, out);
}

// Round 2
// 432.816 us; speedup vs baseline: 6.5889x; 6.5889x over previous
//
#include <hip/hip_runtime.h>
#include <math.h>

#define N_NODES 100000
#define N_EDGES 1600000
#define F 16

// ---------------------------------------------------------------------------
__global__ void zero_int(int* __restrict__ p, int n) {
    int i = blockIdx.x * blockDim.x + threadIdx.x;
    if (i < n) p[i] = 0;
}

// hist[dst]++ for every edge
__global__ void hist_kernel(const int* __restrict__ dst, int* __restrict__ hist) {
    int e = blockIdx.x * blockDim.x + threadIdx.x;
    if (e < N_EDGES) atomicAdd(&hist[dst[e]], 1);
}

// per-256-block sums of hist
__global__ void blocksum_kernel(const int* __restrict__ hist, int n,
                                int* __restrict__ bsum) {
    __shared__ int s[256];
    int t = threadIdx.x;
    int i = blockIdx.x * 256 + t;
    s[t] = (i < n) ? hist[i] : 0;
    __syncthreads();
    for (int off = 128; off > 0; off >>= 1) {
        if (t < off) s[t] += s[t + off];
        __syncthreads();
    }
    if (t == 0) bsum[blockIdx.x] = s[0];
}

// single-block exclusive scan of bsum (nb <= 512)
__global__ void scan_bsum_kernel(int* __restrict__ bsum, int nb) {
    __shared__ int s[512];
    int t = threadIdx.x;
    int v = (t < nb) ? bsum[t] : 0;
    s[t] = v;
    __syncthreads();
    for (int off = 1; off < 512; off <<= 1) {
        int x = (t >= off) ? s[t - off] : 0;
        __syncthreads();
        s[t] += x;
        __syncthreads();
    }
    if (t < nb) bsum[t] = s[t] - v;  // exclusive
}

// per-block exclusive scan + block offset -> rowptr; also copy into cursor
__global__ void scan_write_kernel(const int* __restrict__ hist, int n,
                                  const int* __restrict__ bsum,
                                  int* __restrict__ rowptr,
                                  int* __restrict__ cursor) {
    __shared__ int s[256];
    int t = threadIdx.x;
    int i = blockIdx.x * 256 + t;
    int v = (i < n) ? hist[i] : 0;
    s[t] = v;
    __syncthreads();
    for (int off = 1; off < 256; off <<= 1) {
        int x = (t >= off) ? s[t - off] : 0;
        __syncthreads();
        s[t] += x;
        __syncthreads();
    }
    if (i < n) {
        int r = bsum[blockIdx.x] + s[t] - v;  // exclusive
        rowptr[i] = r;
        cursor[i] = r;
    }
    if (i == 0) rowptr[n] = N_EDGES;
}

// scatter edges into CSR slots: slot = (src, u)
__global__ void scatter_kernel(const int* __restrict__ src,
                               const int* __restrict__ dst,
                               const float* __restrict__ u,
                               int* __restrict__ cursor,
                               uint2* __restrict__ slots) {
    int e = blockIdx.x * blockDim.x + threadIdx.x;
    if (e >= N_EDGES) return;
    int d = dst[e];
    int pos = atomicAdd(&cursor[d], 1);
    slots[pos] = make_uint2((unsigned)src[e], __float_as_uint(u[e]));
}

// ---------------------------------------------------------------------------
// Per-node transform: Y0 = X@W[0], Y1 = X@(W[1]-W[0]), R = X@root + bias
__global__ void node_transform(const float* __restrict__ X, int fin,
                               const float* __restrict__ W,
                               const float* __restrict__ root,
                               const float* __restrict__ bias,
                               float* __restrict__ Y0,
                               float* __restrict__ Y1,
                               float* __restrict__ R,
                               int n_nodes) {
    __shared__ float sW0[48 * 16];
    __shared__ float sWd[48 * 16];
    __shared__ float sR[48 * 16];
    __shared__ float sB[16];
    int t = threadIdx.x;
    for (int i = t; i < fin * 16; i += blockDim.x) {
        float w0 = W[i];
        float w1 = W[fin * 16 + i];
        sW0[i] = w0;
        sWd[i] = w1 - w0;
        sR[i]  = root[i];
    }
    if (t < 16) sB[t] = bias[t];
    __syncthreads();

    int idx = blockIdx.x * blockDim.x + t;
    int n = idx >> 4;
    int o = idx & 15;
    if (n >= n_nodes) return;

    const float* xr = X + (long)n * fin;
    float a0 = 0.0f, a1 = 0.0f, ar = 0.0f;
    for (int f = 0; f < fin; ++f) {
        float xv = xr[f];
        a0 = fmaf(xv, sW0[f * 16 + o], a0);
        a1 = fmaf(xv, sWd[f * 16 + o], a1);
        ar = fmaf(xv, sR[f * 16 + o], ar);
    }
    Y0[idx] = a0;
    Y1[idx] = a1;
    R[idx]  = ar + sB[o];
}

// ---------------------------------------------------------------------------
// Gather-side aggregation. 16 lanes per node, one lane per feature.
// acc = sum_e (Y0[src_e] + u_e*Y1[src_e]); v = acc/max(deg,1) + R; epilogue.
__global__ void aggregate_elu(const int* __restrict__ rowptr,
                              const uint2* __restrict__ slots,
                              const float* __restrict__ Y0,
                              const float* __restrict__ Y1,
                              const float* __restrict__ R,
                              float* __restrict__ H) {
    int t = threadIdx.x;
    int n = blockIdx.x * 16 + (t >> 4);
    int o = t & 15;
    if (n >= N_NODES) return;
    int beg = rowptr[n], end = rowptr[n + 1];
    float acc = 0.0f;
    for (int j = beg; j < end; ++j) {
        uint2 sl = slots[j];
        int s = (int)sl.x;
        float uu = __uint_as_float(sl.y);
        acc += fmaf(uu, Y1[s * 16 + o], Y0[s * 16 + o]);
    }
    float deg = (float)(end - beg);
    float c = deg < 1.0f ? 1.0f : deg;
    float v = acc / c + R[n * 16 + o];
    H[n * 16 + o] = v > 0.0f ? v : expm1f(v);
}

__global__ void aggregate_logsoftmax(const int* __restrict__ rowptr,
                                     const uint2* __restrict__ slots,
                                     const float* __restrict__ Y0,
                                     const float* __restrict__ Y1,
                                     const float* __restrict__ R,
                                     float* __restrict__ out) {
    int t = threadIdx.x;
    int n = blockIdx.x * 16 + (t >> 4);
    int o = t & 15;
    if (n >= N_NODES) return;
    int beg = rowptr[n], end = rowptr[n + 1];
    float acc = 0.0f;
    for (int j = beg; j < end; ++j) {
        uint2 sl = slots[j];
        int s = (int)sl.x;
        float uu = __uint_as_float(sl.y);
        acc += fmaf(uu, Y1[s * 16 + o], Y0[s * 16 + o]);
    }
    float deg = (float)(end - beg);
    float c = deg < 1.0f ? 1.0f : deg;
    float v = acc / c + R[n * 16 + o];

    // log-softmax across the 16 lanes of this node
    float m = v;
#pragma unroll
    for (int mask = 1; mask < 16; mask <<= 1)
        m = fmaxf(m, __shfl_xor(m, mask, 16));
    float e = expf(v - m);
    float s = e;
#pragma unroll
    for (int mask = 1; mask < 16; mask <<= 1)
        s += __shfl_xor(s, mask, 16);
    out[n * 16 + o] = v - (m + logf(s));
}

// ---------------------------------------------------------------------------
extern "C" void kernel_launch(void* const* d_in, const int* in_sizes, int n_in,
                              void* d_out, int out_size, void* d_ws, size_t ws_size,
                              hipStream_t stream) {
    const float* x         = (const float*)d_in[0];
    const float* edge_attr = (const float*)d_in[1];
    const int*   edge_idx  = (const int*)d_in[2];
    const float* W1        = (const float*)d_in[3];
    const float* root1     = (const float*)d_in[4];
    const float* b1        = (const float*)d_in[5];
    const float* W2        = (const float*)d_in[6];
    const float* root2     = (const float*)d_in[7];
    const float* b2        = (const float*)d_in[8];
    float* out = (float*)d_out;

    const int* src = edge_idx;
    const int* dst = edge_idx + N_EDGES;

    const size_t NF = (size_t)N_NODES * F;  // 1.6M floats
    float* ws = (float*)d_ws;
    float* Y0 = ws + 0 * NF;
    float* Y1 = ws + 1 * NF;
    float* R  = ws + 2 * NF;
    float* H  = ws + 3 * NF;
    int* rowptr = (int*)(ws + 4 * NF);          // N+1
    int* cursor = rowptr + (N_NODES + 1);       // N
    int* bsum   = cursor + N_NODES;             // 512
    // align slots to 8 bytes
    size_t islots = 4 * NF + (N_NODES + 1) + N_NODES + 512;
    islots = (islots + 1) & ~(size_t)1;
    uint2* slots = (uint2*)(ws + islots);       // E uint2

    const int BLK = 256;
    const int nScanBlocks = (N_NODES + 255) / 256;  // 391
    dim3 blk(BLK);
    dim3 gEdges((N_EDGES + BLK - 1) / BLK);
    dim3 gNF(((int)NF + BLK - 1) / BLK);
    dim3 gNodes16((N_NODES + 15) / 16);
    dim3 gZeroN((N_NODES + BLK - 1) / BLK);

    // ---- build CSR (shared by both layers) ----
    zero_int<<<gZeroN, blk, 0, stream>>>(cursor, N_NODES);  // cursor doubles as hist
    hist_kernel<<<gEdges, blk, 0, stream>>>(dst, cursor);
    blocksum_kernel<<<nScanBlocks, blk, 0, stream>>>(cursor, N_NODES, bsum);
    scan_bsum_kernel<<<1, 512, 0, stream>>>(bsum, nScanBlocks);
    scan_write_kernel<<<nScanBlocks, blk, 0, stream>>>(cursor, N_NODES, bsum,
                                                       rowptr, cursor);
    scatter_kernel<<<gEdges, blk, 0, stream>>>(src, dst, edge_attr, cursor, slots);

    // ---- layer 1 ----
    node_transform<<<gNF, blk, 0, stream>>>(x, 48, W1, root1, b1, Y0, Y1, R, N_NODES);
    aggregate_elu<<<gNodes16, blk, 0, stream>>>(rowptr, slots, Y0, Y1, R, H);

    // ---- layer 2 ----
    node_transform<<<gNF, blk, 0, stream>>>(H, 16, W2, root2, b2, Y0, Y1, R, N_NODES);
    aggregate_logsoftmax<<<gNodes16, blk, 0, stream>>>(rowptr, slots, Y0, Y1, R, out);
}

// Round 3
// 306.105 us; speedup vs baseline: 9.3163x; 1.4139x over previous
//
#include <hip/hip_runtime.h>
#include <math.h>

#define N_NODES 100000
#define N_EDGES 1600000
#define F 16

// ---------------------------------------------------------------------------
__global__ void init_head(int* __restrict__ head) {
    int i = blockIdx.x * blockDim.x + threadIdx.x;
    if (i < N_NODES) head[i] = -1;
}

// One pass: rec[e] = {src, u, old_head}; head[dst] = e. Coalesced 16B writes.
__global__ void build_links(const int* __restrict__ src,
                            const int* __restrict__ dst,
                            const float* __restrict__ u,
                            int* __restrict__ head,
                            int4* __restrict__ rec) {
    int e = blockIdx.x * blockDim.x + threadIdx.x;
    if (e >= N_EDGES) return;
    int d = dst[e];
    int nx = atomicExch(&head[d], e);
    rec[e] = make_int4(src[e], __float_as_int(u[e]), nx, 0);
}

// ---------------------------------------------------------------------------
// Per-node transform: YP[n*32 + o] = (X@W[0])[n,o]
//                     YP[n*32+16+o] = (X@(W[1]-W[0]))[n,o]
//                     R[n*16+o]     = (X@root)[n,o] + bias[o]
__global__ void node_transform(const float* __restrict__ X, int fin,
                               const float* __restrict__ W,
                               const float* __restrict__ root,
                               const float* __restrict__ bias,
                               float* __restrict__ YP,
                               float* __restrict__ R,
                               int n_nodes) {
    __shared__ float sW0[48 * 16];
    __shared__ float sWd[48 * 16];
    __shared__ float sR[48 * 16];
    __shared__ float sB[16];
    int t = threadIdx.x;
    for (int i = t; i < fin * 16; i += blockDim.x) {
        float w0 = W[i];
        float w1 = W[fin * 16 + i];
        sW0[i] = w0;
        sWd[i] = w1 - w0;
        sR[i]  = root[i];
    }
    if (t < 16) sB[t] = bias[t];
    __syncthreads();

    int idx = blockIdx.x * blockDim.x + t;
    int n = idx >> 4;
    int o = idx & 15;
    if (n >= n_nodes) return;

    const float* xr = X + (long)n * fin;
    float a0 = 0.0f, a1 = 0.0f, ar = 0.0f;
    for (int f = 0; f < fin; ++f) {
        float xv = xr[f];
        a0 = fmaf(xv, sW0[f * 16 + o], a0);
        a1 = fmaf(xv, sWd[f * 16 + o], a1);
        ar = fmaf(xv, sR[f * 16 + o], ar);
    }
    YP[(long)n * 32 + o]      = a0;
    YP[(long)n * 32 + 16 + o] = a1;
    R[(long)n * 16 + o]       = ar + sB[o];
}

// ---------------------------------------------------------------------------
// One chain (node) per lane; 16 features accumulated in registers.
__device__ __forceinline__ void chain_accumulate(int n,
                                                 const int* __restrict__ head,
                                                 const int4* __restrict__ rec,
                                                 const float* __restrict__ YP,
                                                 float acc[16], float* inv_deg) {
#pragma unroll
    for (int i = 0; i < 16; ++i) acc[i] = 0.0f;
    int e = head[n];
    int deg = 0;
    while (e >= 0) {
        int4 r = rec[e];
        float uu = __int_as_float(r.y);
        const float4* y0 = (const float4*)(YP + (long)r.x * 32);
#pragma unroll
        for (int q = 0; q < 4; ++q) {
            float4 a = y0[q];
            float4 b = y0[q + 4];
            acc[4 * q + 0] = fmaf(uu, b.x, a.x) + acc[4 * q + 0];
            acc[4 * q + 1] = fmaf(uu, b.y, a.y) + acc[4 * q + 1];
            acc[4 * q + 2] = fmaf(uu, b.z, a.z) + acc[4 * q + 2];
            acc[4 * q + 3] = fmaf(uu, b.w, a.w) + acc[4 * q + 3];
        }
        ++deg;
        e = r.z;
    }
    *inv_deg = 1.0f / (deg > 0 ? (float)deg : 1.0f);
}

__global__ void aggregate_elu(const int* __restrict__ head,
                              const int4* __restrict__ rec,
                              const float* __restrict__ YP,
                              const float* __restrict__ R,
                              float* __restrict__ H) {
    int n = blockIdx.x * blockDim.x + threadIdx.x;
    if (n >= N_NODES) return;
    float acc[16], inv;
    chain_accumulate(n, head, rec, YP, acc, &inv);

    const float4* rp = (const float4*)(R + (long)n * 16);
    float4* hp = (float4*)(H + (long)n * 16);
#pragma unroll
    for (int q = 0; q < 4; ++q) {
        float4 rr = rp[q];
        float4 o;
        float v;
        v = fmaf(acc[4 * q + 0], inv, rr.x); o.x = v > 0.0f ? v : expm1f(v);
        v = fmaf(acc[4 * q + 1], inv, rr.y); o.y = v > 0.0f ? v : expm1f(v);
        v = fmaf(acc[4 * q + 2], inv, rr.z); o.z = v > 0.0f ? v : expm1f(v);
        v = fmaf(acc[4 * q + 3], inv, rr.w); o.w = v > 0.0f ? v : expm1f(v);
        hp[q] = o;
    }
}

__global__ void aggregate_logsoftmax(const int* __restrict__ head,
                                     const int4* __restrict__ rec,
                                     const float* __restrict__ YP,
                                     const float* __restrict__ R,
                                     float* __restrict__ out) {
    int n = blockIdx.x * blockDim.x + threadIdx.x;
    if (n >= N_NODES) return;
    float acc[16], inv;
    chain_accumulate(n, head, rec, YP, acc, &inv);

    float v[16];
    const float4* rp = (const float4*)(R + (long)n * 16);
#pragma unroll
    for (int q = 0; q < 4; ++q) {
        float4 rr = rp[q];
        v[4 * q + 0] = fmaf(acc[4 * q + 0], inv, rr.x);
        v[4 * q + 1] = fmaf(acc[4 * q + 1], inv, rr.y);
        v[4 * q + 2] = fmaf(acc[4 * q + 2], inv, rr.z);
        v[4 * q + 3] = fmaf(acc[4 * q + 3], inv, rr.w);
    }
    float m = v[0];
#pragma unroll
    for (int i = 1; i < 16; ++i) m = fmaxf(m, v[i]);
    float s = 0.0f;
#pragma unroll
    for (int i = 0; i < 16; ++i) s += expf(v[i] - m);
    float lse = m + logf(s);

    float4* op = (float4*)(out + (long)n * 16);
#pragma unroll
    for (int q = 0; q < 4; ++q) {
        float4 o;
        o.x = v[4 * q + 0] - lse;
        o.y = v[4 * q + 1] - lse;
        o.z = v[4 * q + 2] - lse;
        o.w = v[4 * q + 3] - lse;
        op[q] = o;
    }
}

// ---------------------------------------------------------------------------
extern "C" void kernel_launch(void* const* d_in, const int* in_sizes, int n_in,
                              void* d_out, int out_size, void* d_ws, size_t ws_size,
                              hipStream_t stream) {
    const float* x         = (const float*)d_in[0];
    const float* edge_attr = (const float*)d_in[1];
    const int*   edge_idx  = (const int*)d_in[2];
    const float* W1        = (const float*)d_in[3];
    const float* root1     = (const float*)d_in[4];
    const float* b1        = (const float*)d_in[5];
    const float* W2        = (const float*)d_in[6];
    const float* root2     = (const float*)d_in[7];
    const float* b2        = (const float*)d_in[8];
    float* out = (float*)d_out;

    const int* src = edge_idx;
    const int* dst = edge_idx + N_EDGES;

    // workspace layout (d_ws assumed >= 56 MB, 16B-aligned)
    char* ws = (char*)d_ws;
    int4*  rec  = (int4*)ws;                                   // E * 16B = 25.6 MB
    float* YP   = (float*)(ws + (size_t)N_EDGES * 16);         // N*32 f  = 12.8 MB
    float* R    = YP + (size_t)N_NODES * 32;                   // N*16 f  =  6.4 MB
    float* H    = R  + (size_t)N_NODES * 16;                   // N*16 f  =  6.4 MB
    int*   head = (int*)(H + (size_t)N_NODES * 16);            // N ints  =  0.4 MB

    const int BLK = 256;
    dim3 blk(BLK);
    dim3 gEdges((N_EDGES + BLK - 1) / BLK);
    dim3 gNF((N_NODES * F + BLK - 1) / BLK);
    dim3 gHead((N_NODES + BLK - 1) / BLK);
    // aggregates: 64-thread blocks -> 1563 blocks, even per-CU load
    dim3 blk64(64);
    dim3 gNodes64((N_NODES + 63) / 64);

    init_head<<<gHead, blk, 0, stream>>>(head);
    build_links<<<gEdges, blk, 0, stream>>>(src, dst, edge_attr, head, rec);

    // ---- layer 1 ----
    node_transform<<<gNF, blk, 0, stream>>>(x, 48, W1, root1, b1, YP, R, N_NODES);
    aggregate_elu<<<gNodes64, blk64, 0, stream>>>(head, rec, YP, R, H);

    // ---- layer 2 ----
    node_transform<<<gNF, blk, 0, stream>>>(H, 16, W2, root2, b2, YP, R, N_NODES);
    aggregate_logsoftmax<<<gNodes64, blk64, 0, stream>>>(head, rec, YP, R, out);
}